// Round 9
// baseline (610.438 us; speedup 1.0000x reference)
//
#include <hip/hip_runtime.h>
#include <stdint.h>

#define NFIELD 20
#define HID 1024
#define KEXP 16
#define KX 1280   // nfield * data_nemb
#define KS 320    // nfield * sql_nemb
#define BATCH 8192

typedef __bf16 bf16x8 __attribute__((ext_vector_type(8)));
typedef float f32x4 __attribute__((ext_vector_type(4)));

__device__ __forceinline__ unsigned short f2bf(float f) {
  union { float f; unsigned u; } v; v.f = f;
  unsigned r = v.u + 0x7FFFu + ((v.u >> 16) & 1u);  // RNE
  return (unsigned short)(r >> 16);
}

__device__ __forceinline__ void gload16(const void* g, void* l) {
  __builtin_amdgcn_global_load_lds(
      (const __attribute__((address_space(1))) unsigned int*)(uintptr_t)g,
      (__attribute__((address_space(3))) unsigned int*)(unsigned)(uintptr_t)l,
      16, 0, 0);
}

#define SBAR() asm volatile("s_barrier" ::: "memory")

// ---------------- prep kernels ----------------

__global__ void transpose_cvt(const float* __restrict__ src, unsigned short* __restrict__ dst,
                              int R, int C, long sstride, long dstride) {
  __shared__ float tile[32][33];
  const float* s = src + (size_t)blockIdx.z * sstride;
  unsigned short* d = dst + (size_t)blockIdx.z * dstride;
  const int r0 = blockIdx.y * 32, c0 = blockIdx.x * 32;
  const int tx = threadIdx.x & 31, ty = threadIdx.x >> 5;
#pragma unroll
  for (int i = 0; i < 4; ++i)
    tile[ty + 8 * i][tx] = s[(size_t)(r0 + ty + 8 * i) * C + c0 + tx];
  __syncthreads();
#pragma unroll
  for (int i = 0; i < 4; ++i)
    d[(size_t)(c0 + ty + 8 * i) * R + r0 + tx] = f2bf(tile[tx][ty + 8 * i]);
}

__global__ void gather_x_k(const int* __restrict__ x, const float* __restrict__ tab,
                           unsigned short* __restrict__ out) {
  const int b = blockIdx.x;
  const int f = threadIdx.x >> 4;
  const int q = threadIdx.x & 15;
  const int idx = x[b * NFIELD + f];
  const float4 v = *(const float4*)(tab + (size_t)idx * 64 + q * 4);
  ushort4 o;
  o.x = f2bf(v.x); o.y = f2bf(v.y); o.z = f2bf(v.z); o.w = f2bf(v.w);
  *(ushort4*)(out + (size_t)b * KX + f * 64 + q * 4) = o;
}

__global__ void gather_sql_k(const int* __restrict__ sql, const float* __restrict__ tab,
                             unsigned short* __restrict__ out) {
  const int t = blockIdx.x * 256 + threadIdx.x;
  const int b = t / 80;
  const int r = t - b * 80;
  const int f = r >> 2, q = r & 3;
  const int idx = sql[b * NFIELD + f];
  const float4 v = *(const float4*)(tab + (size_t)idx * 16 + q * 4);
  ushort4 o;
  o.x = f2bf(v.x); o.y = f2bf(v.y); o.z = f2bf(v.z); o.w = f2bf(v.w);
  *(ushort4*)(out + (size_t)b * KS + f * 16 + q * 4) = o;
}

// ---------------- 128x128 / BK=64 producer-consumer GEMM (main experts) ----------------
// C = A[M,K]*Bt[N,K]^T; epilogue relu(acc+eb1) dot eW2 -> atomic out[row*16 + n0>>10].
// 5 waves: waves 0-3 consumers (64x64 each, 2x2), wave 4 producer (all global_load_lds).
// LDS 64 KiB -> 2 blocks/CU. Consumers NEVER wait vmcnt; producer's vmcnt(32) keeps one
// full tile (32 loads) in flight. Step t: {cons: read 16 frags, 16 MFMA kk0} SBAR
// {cons: 16 MFMA kk1 || prod: stage(t+2)->buf[t&1], vmcnt(32)} SBAR.
// Race ledger: consumers' buf[c] reads retire before kk0 (lgkm0) which precedes SBAR-B,
// so producer's stage(t+2) overwrite of buf[c] after SBAR-B is safe; vmcnt(32) retires
// stage(t+1) before the SBAR that opens step t+1's reads of buf[c^1].
template <int KTOT>
__global__ __launch_bounds__(320) void gemm_pc(const __bf16* __restrict__ A,
                                               const __bf16* __restrict__ Bt,
                                               const float* __restrict__ bias,
                                               const float* __restrict__ W2,
                                               float* __restrict__ out) {
  constexpr int NT = KTOT / 64;
  alignas(16) __shared__ __bf16 As[2][128][64];
  alignas(16) __shared__ __bf16 Bs[2][128][64];

  const int tid = threadIdx.x;
  const int lane = tid & 63;
  const int wave = tid >> 6;        // 0..4 (4 = producer)
  const int wr = wave >> 1;         // consumers: M half
  const int wc = wave & 1;          // consumers: N half

  // L2-aware 2-level swizzle (grid 128x64 = 8192 blocks): XCD chunk + 8-wide n-groups,
  // m-major within chunk (B-slab L2-resident, A-panel shared by 8 neighbors).
  const unsigned f = blockIdx.y * gridDim.x + blockIdx.x;
  const unsigned nwg = gridDim.x * gridDim.y;
  const unsigned s = (f >> 3) + (f & 7u) * (nwg >> 3);
  const int m0 = (int)((s & 511u) >> 3) * 128;
  const int n0 = (int)((s >> 9) * 8 + (s & 7u)) * 128;

  // staging map: gload j covers 8 rows; lane l -> row j*8 + l/8, global chunk (l&7)^(l/8)
  // => LDS[r][p] holds global chunk p^(r&7)  (both-sides swizzle, linear LDS dest)
  const int srow = lane >> 3;
  const int sch = (lane & 7) ^ srow;
  const int r15 = lane & 15, g4 = lane >> 4;

  const __bf16* Ag = A + (size_t)(m0 + srow) * KTOT + sch * 8;
  const __bf16* Bg = Bt + (size_t)(n0 + srow) * KTOT + sch * 8;

  auto stage = [&](int t) {  // producer only: 32 gload16 = full 128x64 A + B half-tiles
    const int c = t & 1;
#pragma unroll
    for (int j = 0; j < 16; ++j)
      gload16(Ag + (size_t)(j * 8) * KTOT + t * 64, (void*)&As[c][j * 8][0]);
#pragma unroll
    for (int j = 0; j < 16; ++j)
      gload16(Bg + (size_t)(j * 8) * KTOT + t * 64, (void*)&Bs[c][j * 8][0]);
  };

  f32x4 acc[4][4] = {};

  if (wave == 4) {
    stage(0);
    if (NT > 1) stage(1);
    asm volatile("s_waitcnt vmcnt(32)" ::: "memory");  // tile0 landed; tile1 in flight
  }
  SBAR();

#pragma unroll 2
  for (int t = 0; t < NT; ++t) {
    const int c = t & 1;
    bf16x8 af[4][2], bfr[4][2];
    if (wave < 4) {
#pragma unroll
      for (int mi = 0; mi < 4; ++mi) {
        const int row = wr * 64 + mi * 16 + r15;
#pragma unroll
        for (int kk = 0; kk < 2; ++kk)
          af[mi][kk] = *(const bf16x8*)&As[c][row][((kk * 4 + g4) ^ (row & 7)) * 8];
      }
#pragma unroll
      for (int ni = 0; ni < 4; ++ni) {
        const int row = wc * 64 + ni * 16 + r15;
#pragma unroll
        for (int kk = 0; kk < 2; ++kk)
          bfr[ni][kk] = *(const bf16x8*)&Bs[c][row][((kk * 4 + g4) ^ (row & 7)) * 8];
      }
      // kk0 cluster; compiler inserts lgkmcnt(0) before first MFMA -> all reads retired
      __builtin_amdgcn_s_setprio(1);
#pragma unroll
      for (int mi = 0; mi < 4; ++mi)
#pragma unroll
        for (int ni = 0; ni < 4; ++ni)
          acc[mi][ni] = __builtin_amdgcn_mfma_f32_16x16x32_bf16(af[mi][0], bfr[ni][0], acc[mi][ni], 0, 0, 0);
      __builtin_amdgcn_s_setprio(0);
    }
    SBAR();  // SBAR-B: consumers' buf[c] reads all retired -> producer may overwrite
    if (wave < 4) {
      __builtin_amdgcn_s_setprio(1);
#pragma unroll
      for (int mi = 0; mi < 4; ++mi)
#pragma unroll
        for (int ni = 0; ni < 4; ++ni)
          acc[mi][ni] = __builtin_amdgcn_mfma_f32_16x16x32_bf16(af[mi][1], bfr[ni][1], acc[mi][ni], 0, 0, 0);
      __builtin_amdgcn_s_setprio(0);
    } else {
      if (t + 2 < NT) {
        stage(t + 2);  // into buf[c]
        asm volatile("s_waitcnt vmcnt(32)" ::: "memory");  // stage(t+1) retired
      } else if (t + 1 < NT) {
        asm volatile("s_waitcnt vmcnt(0)" ::: "memory");   // drain last stage
      }
    }
    SBAR();  // SBAR-A: buf[c^1] = tile t+1 ready
  }

  if (wave == 4) return;  // producer: no epilogue

  // epilogue: relu(acc+bias), weighted column reduce, atomic accumulate (experts)
  int ncol[4];
  float bsv[4];
#pragma unroll
  for (int ni = 0; ni < 4; ++ni) {
    ncol[ni] = n0 + wc * 64 + ni * 16 + r15;  // C/D: col = lane&15
    bsv[ni] = bias[ncol[ni]];
  }
#pragma unroll
  for (int mi = 0; mi < 4; ++mi)
#pragma unroll
    for (int ni = 0; ni < 4; ++ni)
#pragma unroll
      for (int j = 0; j < 4; ++j) {
        float v = acc[mi][ni][j] + bsv[ni];
        acc[mi][ni][j] = v > 0.f ? v : 0.f;
      }
  float w4[4];
#pragma unroll
  for (int ni = 0; ni < 4; ++ni) w4[ni] = W2[ncol[ni]];
  const int oc = n0 >> 10;
#pragma unroll
  for (int mi = 0; mi < 4; ++mi)
#pragma unroll
    for (int j = 0; j < 4; ++j) {
      float s = acc[mi][0][j] * w4[0] + acc[mi][1][j] * w4[1] +
                acc[mi][2][j] * w4[2] + acc[mi][3][j] * w4[3];
      s += __shfl_xor(s, 1);
      s += __shfl_xor(s, 2);
      s += __shfl_xor(s, 4);
      s += __shfl_xor(s, 8);
      if (r15 == 0) {
        const int row = m0 + wr * 64 + mi * 16 + g4 * 4 + j;  // C/D: row=(lane>>4)*4+reg
        atomicAdd(&out[row * KEXP + oc], s);
      }
    }
}

// ---------------- 128x128 / BK=64 fused GEMM (gate, NJO=16) — R7-proven ----------------
template <int NJO, int KTOT>
__global__ __launch_bounds__(256, 2) void gemm_k(const __bf16* __restrict__ A,
                                                 const __bf16* __restrict__ Bt,
                                                 const float* __restrict__ bias,
                                                 const float* __restrict__ W2,
                                                 float* __restrict__ out) {
  constexpr int NT = KTOT / 64;
  alignas(16) __shared__ __bf16 As[2][128][64];
  alignas(16) __shared__ __bf16 Bs[2][128][64];

  const int tid = threadIdx.x;
  const int lane = tid & 63;
  const int wave = tid >> 6;
  const int wr = wave >> 1, wc = wave & 1;

  const unsigned f = blockIdx.y * gridDim.x + blockIdx.x;
  const unsigned nwg = gridDim.x * gridDim.y;
  const unsigned s = (f >> 3) + (f & 7u) * (nwg >> 3);
  const int m0 = (int)((s & 511u) >> 3) * 128;
  const int n0 = (int)((s >> 9) * 8 + (s & 7u)) * 128;

  const int srow = lane >> 3;
  const int sch = (lane & 7) ^ srow;
  const int r15 = lane & 15, g4 = lane >> 4;

  const __bf16* Ag = A + (size_t)(m0 + wave * 32 + srow) * KTOT + sch * 8;
  const __bf16* Bg = Bt + (size_t)(n0 + wave * 32 + srow) * KTOT + sch * 8;

  auto stage = [&](int t) {
    const int c = t & 1;
#pragma unroll
    for (int j = 0; j < 4; ++j)
      gload16(Ag + (size_t)(j * 8) * KTOT + t * 64, (void*)&As[c][wave * 32 + j * 8][0]);
#pragma unroll
    for (int j = 0; j < 4; ++j)
      gload16(Bg + (size_t)(j * 8) * KTOT + t * 64, (void*)&Bs[c][wave * 32 + j * 8][0]);
  };

  f32x4 acc[4][4] = {};

  stage(0);
  if (NT > 1) { stage(1); asm volatile("s_waitcnt vmcnt(8)" ::: "memory"); }
  else        {           asm volatile("s_waitcnt vmcnt(0)" ::: "memory"); }
  SBAR();

#pragma unroll 2
  for (int t = 0; t < NT; ++t) {
    const int c = t & 1;
    bf16x8 af[4][2], bfr[4][2];
#pragma unroll
    for (int mi = 0; mi < 4; ++mi) {
      const int row = wr * 64 + mi * 16 + r15;
#pragma unroll
      for (int kk = 0; kk < 2; ++kk)
        af[mi][kk] = *(const bf16x8*)&As[c][row][((kk * 4 + g4) ^ (row & 7)) * 8];
    }
#pragma unroll
    for (int ni = 0; ni < 4; ++ni) {
      const int row = wc * 64 + ni * 16 + r15;
#pragma unroll
      for (int kk = 0; kk < 2; ++kk)
        bfr[ni][kk] = *(const bf16x8*)&Bs[c][row][((kk * 4 + g4) ^ (row & 7)) * 8];
    }
    __builtin_amdgcn_s_setprio(1);
#pragma unroll
    for (int mi = 0; mi < 4; ++mi)
#pragma unroll
      for (int ni = 0; ni < 4; ++ni)
        acc[mi][ni] = __builtin_amdgcn_mfma_f32_16x16x32_bf16(af[mi][0], bfr[ni][0], acc[mi][ni], 0, 0, 0);
    __builtin_amdgcn_s_setprio(0);
    SBAR();
    if (t + 2 < NT) stage(t + 2);
    __builtin_amdgcn_s_setprio(1);
#pragma unroll
    for (int mi = 0; mi < 4; ++mi)
#pragma unroll
      for (int ni = 0; ni < 4; ++ni)
        acc[mi][ni] = __builtin_amdgcn_mfma_f32_16x16x32_bf16(af[mi][1], bfr[ni][1], acc[mi][ni], 0, 0, 0);
    __builtin_amdgcn_s_setprio(0);
    if (t + 2 < NT) asm volatile("s_waitcnt vmcnt(8)" ::: "memory");
    else            asm volatile("s_waitcnt vmcnt(0)" ::: "memory");
    SBAR();
  }

  int ncol[4];
  float bsv[4];
#pragma unroll
  for (int ni = 0; ni < 4; ++ni) {
    ncol[ni] = n0 + wc * 64 + ni * 16 + r15;
    bsv[ni] = bias[ncol[ni]];
  }
#pragma unroll
  for (int mi = 0; mi < 4; ++mi)
#pragma unroll
    for (int ni = 0; ni < 4; ++ni)
#pragma unroll
      for (int j = 0; j < 4; ++j) {
        float v = acc[mi][ni][j] + bsv[ni];
        acc[mi][ni][j] = v > 0.f ? v : 0.f;
      }
#pragma unroll
  for (int jo = 0; jo < NJO; ++jo) {
    float w4[4];
#pragma unroll
    for (int ni = 0; ni < 4; ++ni)
      w4[ni] = (NJO == 1) ? W2[ncol[ni]] : W2[ncol[ni] * NJO + jo];
#pragma unroll
    for (int mi = 0; mi < 4; ++mi)
#pragma unroll
      for (int j = 0; j < 4; ++j) {
        float s = acc[mi][0][j] * w4[0] + acc[mi][1][j] * w4[1] +
                  acc[mi][2][j] * w4[2] + acc[mi][3][j] * w4[3];
        s += __shfl_xor(s, 1);
        s += __shfl_xor(s, 2);
        s += __shfl_xor(s, 4);
        s += __shfl_xor(s, 8);
        if (r15 == 0) {
          const int row = m0 + wr * 64 + mi * 16 + g4 * 4 + j;
          const int oc = (NJO == 1) ? (n0 >> 10) : jo;
          atomicAdd(&out[row * KEXP + oc], s);
        }
      }
  }
}

// ---------------- entmax (alpha=1.5, 50 bisect iters) + combine + gate colsums ------------
__global__ void entmax_combine(const float* __restrict__ gacc, const float* __restrict__ gb2,
                               const float* __restrict__ yk, const float* __restrict__ eb2,
                               float* __restrict__ y, double* __restrict__ colsum) {
  const int b = blockIdx.x * 256 + threadIdx.x;
  float x[16];
  float mx = -3.4e38f;
#pragma unroll
  for (int j = 0; j < 16; ++j) {
    x[j] = (gacc[b * 16 + j] + gb2[j]) * 0.5f;  // * (alpha-1)
    mx = fmaxf(mx, x[j]);
  }
  float lo = mx - 1.0f, hi = mx - 0.25f;  // d^(1-alpha) = 16^-0.5
  float flo = -1.0f;
#pragma unroll
  for (int j = 0; j < 16; ++j) {
    float d = x[j] - lo; d = d > 0.f ? d : 0.f;
    flo += d * d;
  }
  for (int it = 0; it < 50; ++it) {
    const float tm = 0.5f * (lo + hi);
    float fm = -1.0f;
#pragma unroll
    for (int j = 0; j < 16; ++j) {
      float d = x[j] - tm; d = d > 0.f ? d : 0.f;
      fm += d * d;
    }
    if (fm * flo >= 0.f) { lo = tm; flo = fm; } else { hi = tm; }
  }
  const float tm = 0.5f * (lo + hi);
  float p[16], ps = 0.f;
#pragma unroll
  for (int j = 0; j < 16; ++j) {
    float d = x[j] - tm; d = d > 0.f ? d : 0.f;
    p[j] = d * d; ps += p[j];
  }
  const float inv = 1.0f / ps;
  float yv = 0.f;
#pragma unroll
  for (int j = 0; j < 16; ++j) {
    p[j] *= inv;
    yv += p[j] * (yk[b * 16 + j] + eb2[j]);
  }
  y[b] = yv;

  const int lane = threadIdx.x & 63, wv = threadIdx.x >> 6;
  __shared__ float red[4][16];
#pragma unroll
  for (int j = 0; j < 16; ++j) {
    float v = p[j];
    v += __shfl_xor(v, 1);  v += __shfl_xor(v, 2);  v += __shfl_xor(v, 4);
    v += __shfl_xor(v, 8);  v += __shfl_xor(v, 16); v += __shfl_xor(v, 32);
    if (lane == 0) red[wv][j] = v;
  }
  __syncthreads();
  if (threadIdx.x < 16) {
    double s = (double)red[0][threadIdx.x] + (double)red[1][threadIdx.x] +
               (double)red[2][threadIdx.x] + (double)red[3][threadIdx.x];
    atomicAdd(&colsum[threadIdx.x], s);
  }
}

__global__ void loss_k(const double* __restrict__ colsum, float* __restrict__ out) {
  if (threadIdx.x == 0 && blockIdx.x == 0) {
    double m = 0.0;
    for (int k = 0; k < 16; ++k) m += colsum[k];
    m *= (1.0 / 16.0);
    double var = 0.0;
    for (int k = 0; k < 16; ++k) { const double d = colsum[k] - m; var += d * d; }
    var *= (1.0 / 15.0);  // ddof=1
    out[0] = (float)(var / (m * m + 1e-10));
  }
}

// ---------------- launch ----------------
extern "C" void kernel_launch(void* const* d_in, const int* in_sizes, int n_in,
                              void* d_out, int out_size, void* d_ws, size_t ws_size,
                              hipStream_t stream) {
  const int*   x    = (const int*)d_in[0];
  const int*   sql  = (const int*)d_in[1];
  const float* sqlT = (const float*)d_in[2];
  const float* inT  = (const float*)d_in[3];
  const float* gW1  = (const float*)d_in[4];
  const float* gb1  = (const float*)d_in[5];
  const float* gW2  = (const float*)d_in[6];
  const float* gb2  = (const float*)d_in[7];
  const float* eW1  = (const float*)d_in[8];
  const float* eb1  = (const float*)d_in[9];
  const float* eW2  = (const float*)d_in[10];
  const float* eb2  = (const float*)d_in[11];

  char* ws = (char*)d_ws;
  unsigned short* eW1T = (unsigned short*)(ws);              // [16384][1280] bf16
  unsigned short* xemb = (unsigned short*)(ws + 41943040);   // [8192][1280]
  unsigned short* semb = (unsigned short*)(ws + 62914560);   // [8192][320]
  unsigned short* gW1T = (unsigned short*)(ws + 68157440);   // [1024][320]
  float*  yk     = (float*)(ws + 68812800);                  // [8192][16]
  float*  gacc   = (float*)(ws + 69337088);                  // [8192][16]
  double* colsum = (double*)(ws + 69861376);                 // [16]

  hipMemsetAsync(yk, 0, 524288 * 2 + 128, stream);

  transpose_cvt<<<dim3(32, 40, 16), 256, 0, stream>>>(eW1, eW1T, 1280, 1024, 1280L * 1024, 1024L * 1280);
  transpose_cvt<<<dim3(32, 10, 1), 256, 0, stream>>>(gW1, gW1T, 320, 1024, 0, 0);
  gather_x_k<<<BATCH, 320, 0, stream>>>(x, inT, xemb);
  gather_sql_k<<<BATCH * 80 / 256, 256, 0, stream>>>(sql, sqlT, semb);

  gemm_pc<KX><<<dim3(16384 / 128, BATCH / 128), 320, 0, stream>>>(
      (const __bf16*)xemb, (const __bf16*)eW1T, eb1, eW2, yk);
  gemm_k<16, KS><<<dim3(HID / 128, BATCH / 128), 256, 0, stream>>>(
      (const __bf16*)semb, (const __bf16*)gW1T, gb1, gW2, gacc);

  entmax_combine<<<BATCH / 256, 256, 0, stream>>>(gacc, gb2, yk, eb2, (float*)d_out, colsum);
  loss_k<<<1, 64, 0, stream>>>(colsum, (float*)d_out + BATCH);
}

// Round 10
// 516.973 us; speedup vs baseline: 1.1808x; 1.1808x over previous
//
#include <hip/hip_runtime.h>
#include <stdint.h>

#define NFIELD 20
#define HID 1024
#define KEXP 16
#define KX 1280   // nfield * data_nemb
#define KS 320    // nfield * sql_nemb
#define BATCH 8192

typedef __bf16 bf16x8 __attribute__((ext_vector_type(8)));
typedef float f32x4 __attribute__((ext_vector_type(4)));

__device__ __forceinline__ unsigned short f2bf(float f) {
  union { float f; unsigned u; } v; v.f = f;
  unsigned r = v.u + 0x7FFFu + ((v.u >> 16) & 1u);  // RNE
  return (unsigned short)(r >> 16);
}

__device__ __forceinline__ void gload16(const void* g, void* l) {
  __builtin_amdgcn_global_load_lds(
      (const __attribute__((address_space(1))) unsigned int*)(uintptr_t)g,
      (__attribute__((address_space(3))) unsigned int*)(unsigned)(uintptr_t)l,
      16, 0, 0);
}

#define SBAR() asm volatile("s_barrier" ::: "memory")

// ---------------- prep kernels ----------------

__global__ void transpose_cvt(const float* __restrict__ src, unsigned short* __restrict__ dst,
                              int R, int C, long sstride, long dstride) {
  __shared__ float tile[32][33];
  const float* s = src + (size_t)blockIdx.z * sstride;
  unsigned short* d = dst + (size_t)blockIdx.z * dstride;
  const int r0 = blockIdx.y * 32, c0 = blockIdx.x * 32;
  const int tx = threadIdx.x & 31, ty = threadIdx.x >> 5;
#pragma unroll
  for (int i = 0; i < 4; ++i)
    tile[ty + 8 * i][tx] = s[(size_t)(r0 + ty + 8 * i) * C + c0 + tx];
  __syncthreads();
#pragma unroll
  for (int i = 0; i < 4; ++i)
    d[(size_t)(c0 + ty + 8 * i) * R + r0 + tx] = f2bf(tile[tx][ty + 8 * i]);
}

__global__ void gather_x_k(const int* __restrict__ x, const float* __restrict__ tab,
                           unsigned short* __restrict__ out) {
  const int b = blockIdx.x;
  const int f = threadIdx.x >> 4;
  const int q = threadIdx.x & 15;
  const int idx = x[b * NFIELD + f];
  const float4 v = *(const float4*)(tab + (size_t)idx * 64 + q * 4);
  ushort4 o;
  o.x = f2bf(v.x); o.y = f2bf(v.y); o.z = f2bf(v.z); o.w = f2bf(v.w);
  *(ushort4*)(out + (size_t)b * KX + f * 64 + q * 4) = o;
}

__global__ void gather_sql_k(const int* __restrict__ sql, const float* __restrict__ tab,
                             unsigned short* __restrict__ out) {
  const int t = blockIdx.x * 256 + threadIdx.x;
  const int b = t / 80;
  const int r = t - b * 80;
  const int f = r >> 2, q = r & 3;
  const int idx = sql[b * NFIELD + f];
  const float4 v = *(const float4*)(tab + (size_t)idx * 16 + q * 4);
  ushort4 o;
  o.x = f2bf(v.x); o.y = f2bf(v.y); o.z = f2bf(v.z); o.w = f2bf(v.w);
  *(ushort4*)(out + (size_t)b * KS + f * 16 + q * 4) = o;
}

// ---------------- 256x256 / BK=64 8-phase GEMM (main experts) ----------------
// Identical to R8 EXCEPT: no sched_barrier(0) (m141: order-pinning regression);
// + lgkmcnt(8) partial wait in the 12-read phases (p1/p5), per m201 template.
// vmcnt(6) ledger re-verified: at p4, retires Am1(t1) just before p5 uses it;
// at p8, retires all of tile t0+2 before next-iter p1; 6 loads always in flight.
template <int KTOT>
__global__ __launch_bounds__(512, 2) void gemm256(const __bf16* __restrict__ A,
                                                  const __bf16* __restrict__ Bt,
                                                  const float* __restrict__ bias,
                                                  const float* __restrict__ W2,
                                                  float* __restrict__ out) {
  constexpr int NT = KTOT / 64;
  static_assert(NT % 2 == 0 && NT >= 4, "even NT only");
  alignas(16) __shared__ __bf16 As[2][256][64];
  alignas(16) __shared__ __bf16 Bs[2][256][64];

  const int tid = threadIdx.x;
  const int lane = tid & 63;
  const int wave = tid >> 6;        // 0..7
  const int wr = wave >> 2;         // 0..1 : M half (128 rows)
  const int wc = wave & 3;          // 0..3 : N quarter (64 cols)

  // XCD swizzle + 8-wide n-groups, m-major within chunk (grid 64x32)
  const unsigned f = blockIdx.y * gridDim.x + blockIdx.x;
  const unsigned c8 = f >> 3;
  const int n0 = (int)((f & 7u) * 8 + (c8 & 7u)) * 256;
  const int m0 = (int)(c8 >> 3) * 256;

  const int srow = lane >> 3;
  const int sch = (lane & 7) ^ srow;   // pre-swizzled global chunk
  const int r15 = lane & 15, g4 = lane >> 4;

  const __bf16* Ag = A + (size_t)(m0 + srow) * KTOT + sch * 8;
  const __bf16* Bg = Bt + (size_t)(n0 + srow) * KTOT + sch * 8;
  const int k2 = wave * 2;

  // A-half mh rows: {mh*64+0..63, 128+mh*64+0..63}; B-half nh rows: {q*64+nh*32+0..31}
  auto stA = [&](int t, int mh) {
    if (t >= NT) return;
    __bf16* base = &As[t & 1][0][0];
#pragma unroll
    for (int j = 0; j < 2; ++j) {
      const int k = k2 + j;
      const int r = ((k >> 3) << 7) + mh * 64 + (k & 7) * 8;
      gload16(Ag + (size_t)r * KTOT + t * 64, (void*)(base + r * 64));
    }
  };
  auto stB = [&](int t, int nh) {
    if (t >= NT) return;
    __bf16* base = &Bs[t & 1][0][0];
#pragma unroll
    for (int j = 0; j < 2; ++j) {
      const int k = k2 + j;
      const int r = (k >> 2) * 64 + nh * 32 + (k & 3) * 8;
      gload16(Bg + (size_t)r * KTOT + t * 64, (void*)(base + r * 64));
    }
  };
  auto rdA = [&](int c, int mh, bf16x8 (&af)[4][2]) {
#pragma unroll
    for (int mi = 0; mi < 4; ++mi) {
      const int row = wr * 128 + mh * 64 + mi * 16 + r15;
#pragma unroll
      for (int kk = 0; kk < 2; ++kk)
        af[mi][kk] = *(const bf16x8*)&As[c][row][((kk * 4 + g4) ^ (row & 7)) * 8];
    }
  };
  auto rdB = [&](int c, int nh, bf16x8 (&bb)[2][2]) {
#pragma unroll
    for (int ni = 0; ni < 2; ++ni) {
      const int row = wc * 64 + nh * 32 + ni * 16 + r15;
#pragma unroll
      for (int kk = 0; kk < 2; ++kk)
        bb[ni][kk] = *(const bf16x8*)&Bs[c][row][((kk * 4 + g4) ^ (row & 7)) * 8];
    }
  };

  f32x4 acc[8][4] = {};
  bf16x8 af[4][2], b0[2][2], b1[2][2];

#define MM(AF, BB, MH, NH)                                                        \
  __builtin_amdgcn_s_setprio(1);                                                  \
  _Pragma("unroll") for (int mi = 0; mi < 4; ++mi)                                \
  _Pragma("unroll") for (int ni = 0; ni < 2; ++ni)                                \
  _Pragma("unroll") for (int kk = 0; kk < 2; ++kk)                                \
      acc[(MH)*4 + mi][(NH)*2 + ni] = __builtin_amdgcn_mfma_f32_16x16x32_bf16(    \
          AF[mi][kk], BB[ni][kk], acc[(MH)*4 + mi][(NH)*2 + ni], 0, 0, 0);        \
  __builtin_amdgcn_s_setprio(0);

  // prologue: tile0 all 4 halves, tile1 first 3; 6 loads in flight after wait
  stA(0, 0); stB(0, 0); stB(0, 1); stA(0, 1);
  stA(1, 0); stB(1, 0); stB(1, 1);
  asm volatile("s_waitcnt vmcnt(6)" ::: "memory");
  SBAR();

  for (int i = 0; i < NT / 2; ++i) {
    const int t0 = 2 * i, t1 = 2 * i + 1;
    // p1: q0(t0)  reads A-m0,B-n0(buf0) [12 reads]; stage Am1(t1)
    rdA(0, 0, af); rdB(0, 0, b0);
    stA(t1, 1);
    asm volatile("s_waitcnt lgkmcnt(8)" ::: "memory");
    SBAR();
    MM(af, b0, 0, 0);
    SBAR();
    // p2: q1(t0)  reads B-n1 [4]; stage Am0(t0+2)
    rdB(0, 1, b1);
    stA(t0 + 2, 0);
    SBAR();
    MM(af, b1, 0, 1);
    SBAR();
    // p3: q2(t0)  reads A-m1 [8]; stage Bn0(t0+2)
    rdA(0, 1, af);
    stB(t0 + 2, 0);
    SBAR();
    MM(af, b1, 1, 1);
    SBAR();
    // p4: q3(t0)  no reads; stage Bn1(t0+2); vmcnt(6)
    stB(t0 + 2, 1);
    SBAR();
    MM(af, b0, 1, 0);
    if (t0 + 2 < NT) asm volatile("s_waitcnt vmcnt(6)" ::: "memory");
    else             asm volatile("s_waitcnt vmcnt(0)" ::: "memory");
    SBAR();
    // p5: q0(t1)  reads buf1 [12]; stage Am1(t0+2)
    rdA(1, 0, af); rdB(1, 0, b0);
    stA(t0 + 2, 1);
    asm volatile("s_waitcnt lgkmcnt(8)" ::: "memory");
    SBAR();
    MM(af, b0, 0, 0);
    SBAR();
    // p6: q1(t1) [4]; stage Am0(t1+2)
    rdB(1, 1, b1);
    stA(t1 + 2, 0);
    SBAR();
    MM(af, b1, 0, 1);
    SBAR();
    // p7: q2(t1) [8]; stage Bn0(t1+2)
    rdA(1, 1, af);
    stB(t1 + 2, 0);
    SBAR();
    MM(af, b1, 1, 1);
    SBAR();
    // p8: q3(t1); stage Bn1(t1+2); vmcnt(6)
    stB(t1 + 2, 1);
    SBAR();
    MM(af, b0, 1, 0);
    if (t1 + 2 < NT) asm volatile("s_waitcnt vmcnt(6)" ::: "memory");
    else             asm volatile("s_waitcnt vmcnt(0)" ::: "memory");
    SBAR();
  }
#undef MM

  // epilogue: relu(acc+bias), weighted column reduce, atomic accumulate (experts)
  int ncol[4];
  float bsv[4];
#pragma unroll
  for (int b = 0; b < 4; ++b) {
    ncol[b] = n0 + wc * 64 + (b >> 1) * 32 + (b & 1) * 16 + r15;  // C/D: col = lane&15
    bsv[b] = bias[ncol[b]];
  }
#pragma unroll
  for (int a = 0; a < 8; ++a)
#pragma unroll
    for (int b = 0; b < 4; ++b)
#pragma unroll
      for (int j = 0; j < 4; ++j) {
        float v = acc[a][b][j] + bsv[b];
        acc[a][b][j] = v > 0.f ? v : 0.f;
      }
  float w4[4];
#pragma unroll
  for (int b = 0; b < 4; ++b) w4[b] = W2[ncol[b]];
  const int oc = n0 >> 10;
#pragma unroll
  for (int a = 0; a < 8; ++a)
#pragma unroll
    for (int j = 0; j < 4; ++j) {
      float s = acc[a][0][j] * w4[0] + acc[a][1][j] * w4[1] +
                acc[a][2][j] * w4[2] + acc[a][3][j] * w4[3];
      s += __shfl_xor(s, 1);
      s += __shfl_xor(s, 2);
      s += __shfl_xor(s, 4);
      s += __shfl_xor(s, 8);
      if (r15 == 0) {
        const int row = m0 + wr * 128 + (a >> 2) * 64 + (a & 3) * 16 + g4 * 4 + j;
        atomicAdd(&out[row * KEXP + oc], s);
      }
    }
}

// ---------------- 128x128 / BK=64 fused GEMM (gate, NJO=16) — R7-proven ----------------
template <int NJO, int KTOT>
__global__ __launch_bounds__(256, 2) void gemm_k(const __bf16* __restrict__ A,
                                                 const __bf16* __restrict__ Bt,
                                                 const float* __restrict__ bias,
                                                 const float* __restrict__ W2,
                                                 float* __restrict__ out) {
  constexpr int NT = KTOT / 64;
  alignas(16) __shared__ __bf16 As[2][128][64];
  alignas(16) __shared__ __bf16 Bs[2][128][64];

  const int tid = threadIdx.x;
  const int lane = tid & 63;
  const int wave = tid >> 6;
  const int wr = wave >> 1, wc = wave & 1;

  const unsigned f = blockIdx.y * gridDim.x + blockIdx.x;
  const unsigned nwg = gridDim.x * gridDim.y;
  const unsigned s = (f >> 3) + (f & 7u) * (nwg >> 3);
  const int m0 = (int)((s & 511u) >> 3) * 128;
  const int n0 = (int)((s >> 9) * 8 + (s & 7u)) * 128;

  const int srow = lane >> 3;
  const int sch = (lane & 7) ^ srow;
  const int r15 = lane & 15, g4 = lane >> 4;

  const __bf16* Ag = A + (size_t)(m0 + wave * 32 + srow) * KTOT + sch * 8;
  const __bf16* Bg = Bt + (size_t)(n0 + wave * 32 + srow) * KTOT + sch * 8;

  auto stage = [&](int t) {
    const int c = t & 1;
#pragma unroll
    for (int j = 0; j < 4; ++j)
      gload16(Ag + (size_t)(j * 8) * KTOT + t * 64, (void*)&As[c][wave * 32 + j * 8][0]);
#pragma unroll
    for (int j = 0; j < 4; ++j)
      gload16(Bg + (size_t)(j * 8) * KTOT + t * 64, (void*)&Bs[c][wave * 32 + j * 8][0]);
  };

  f32x4 acc[4][4] = {};

  stage(0);
  if (NT > 1) { stage(1); asm volatile("s_waitcnt vmcnt(8)" ::: "memory"); }
  else        {           asm volatile("s_waitcnt vmcnt(0)" ::: "memory"); }
  SBAR();

#pragma unroll 2
  for (int t = 0; t < NT; ++t) {
    const int c = t & 1;
    bf16x8 af[4][2], bfr[4][2];
#pragma unroll
    for (int mi = 0; mi < 4; ++mi) {
      const int row = wr * 64 + mi * 16 + r15;
#pragma unroll
      for (int kk = 0; kk < 2; ++kk)
        af[mi][kk] = *(const bf16x8*)&As[c][row][((kk * 4 + g4) ^ (row & 7)) * 8];
    }
#pragma unroll
    for (int ni = 0; ni < 4; ++ni) {
      const int row = wc * 64 + ni * 16 + r15;
#pragma unroll
      for (int kk = 0; kk < 2; ++kk)
        bfr[ni][kk] = *(const bf16x8*)&Bs[c][row][((kk * 4 + g4) ^ (row & 7)) * 8];
    }
    __builtin_amdgcn_s_setprio(1);
#pragma unroll
    for (int mi = 0; mi < 4; ++mi)
#pragma unroll
      for (int ni = 0; ni < 4; ++ni)
        acc[mi][ni] = __builtin_amdgcn_mfma_f32_16x16x32_bf16(af[mi][0], bfr[ni][0], acc[mi][ni], 0, 0, 0);
    __builtin_amdgcn_s_setprio(0);
    SBAR();
    if (t + 2 < NT) stage(t + 2);
    __builtin_amdgcn_s_setprio(1);
#pragma unroll
    for (int mi = 0; mi < 4; ++mi)
#pragma unroll
      for (int ni = 0; ni < 4; ++ni)
        acc[mi][ni] = __builtin_amdgcn_mfma_f32_16x16x32_bf16(af[mi][1], bfr[ni][1], acc[mi][ni], 0, 0, 0);
    __builtin_amdgcn_s_setprio(0);
    if (t + 2 < NT) asm volatile("s_waitcnt vmcnt(8)" ::: "memory");
    else            asm volatile("s_waitcnt vmcnt(0)" ::: "memory");
    SBAR();
  }

  int ncol[4];
  float bsv[4];
#pragma unroll
  for (int ni = 0; ni < 4; ++ni) {
    ncol[ni] = n0 + wc * 64 + ni * 16 + r15;
    bsv[ni] = bias[ncol[ni]];
  }
#pragma unroll
  for (int mi = 0; mi < 4; ++mi)
#pragma unroll
    for (int ni = 0; ni < 4; ++ni)
#pragma unroll
      for (int j = 0; j < 4; ++j) {
        float v = acc[mi][ni][j] + bsv[ni];
        acc[mi][ni][j] = v > 0.f ? v : 0.f;
      }
#pragma unroll
  for (int jo = 0; jo < NJO; ++jo) {
    float w4[4];
#pragma unroll
    for (int ni = 0; ni < 4; ++ni)
      w4[ni] = (NJO == 1) ? W2[ncol[ni]] : W2[ncol[ni] * NJO + jo];
#pragma unroll
    for (int mi = 0; mi < 4; ++mi)
#pragma unroll
      for (int j = 0; j < 4; ++j) {
        float s = acc[mi][0][j] * w4[0] + acc[mi][1][j] * w4[1] +
                  acc[mi][2][j] * w4[2] + acc[mi][3][j] * w4[3];
        s += __shfl_xor(s, 1);
        s += __shfl_xor(s, 2);
        s += __shfl_xor(s, 4);
        s += __shfl_xor(s, 8);
        if (r15 == 0) {
          const int row = m0 + wr * 64 + mi * 16 + g4 * 4 + j;
          const int oc = (NJO == 1) ? (n0 >> 10) : jo;
          atomicAdd(&out[row * KEXP + oc], s);
        }
      }
  }
}

// ---------------- entmax (alpha=1.5, 50 bisect iters) + combine + gate colsums ------------
__global__ void entmax_combine(const float* __restrict__ gacc, const float* __restrict__ gb2,
                               const float* __restrict__ yk, const float* __restrict__ eb2,
                               float* __restrict__ y, double* __restrict__ colsum) {
  const int b = blockIdx.x * 256 + threadIdx.x;
  float x[16];
  float mx = -3.4e38f;
#pragma unroll
  for (int j = 0; j < 16; ++j) {
    x[j] = (gacc[b * 16 + j] + gb2[j]) * 0.5f;  // * (alpha-1)
    mx = fmaxf(mx, x[j]);
  }
  float lo = mx - 1.0f, hi = mx - 0.25f;  // d^(1-alpha) = 16^-0.5
  float flo = -1.0f;
#pragma unroll
  for (int j = 0; j < 16; ++j) {
    float d = x[j] - lo; d = d > 0.f ? d : 0.f;
    flo += d * d;
  }
  for (int it = 0; it < 50; ++it) {
    const float tm = 0.5f * (lo + hi);
    float fm = -1.0f;
#pragma unroll
    for (int j = 0; j < 16; ++j) {
      float d = x[j] - tm; d = d > 0.f ? d : 0.f;
      fm += d * d;
    }
    if (fm * flo >= 0.f) { lo = tm; flo = fm; } else { hi = tm; }
  }
  const float tm = 0.5f * (lo + hi);
  float p[16], ps = 0.f;
#pragma unroll
  for (int j = 0; j < 16; ++j) {
    float d = x[j] - tm; d = d > 0.f ? d : 0.f;
    p[j] = d * d; ps += p[j];
  }
  const float inv = 1.0f / ps;
  float yv = 0.f;
#pragma unroll
  for (int j = 0; j < 16; ++j) {
    p[j] *= inv;
    yv += p[j] * (yk[b * 16 + j] + eb2[j]);
  }
  y[b] = yv;

  const int lane = threadIdx.x & 63, wv = threadIdx.x >> 6;
  __shared__ float red[4][16];
#pragma unroll
  for (int j = 0; j < 16; ++j) {
    float v = p[j];
    v += __shfl_xor(v, 1);  v += __shfl_xor(v, 2);  v += __shfl_xor(v, 4);
    v += __shfl_xor(v, 8);  v += __shfl_xor(v, 16); v += __shfl_xor(v, 32);
    if (lane == 0) red[wv][j] = v;
  }
  __syncthreads();
  if (threadIdx.x < 16) {
    double s = (double)red[0][threadIdx.x] + (double)red[1][threadIdx.x] +
               (double)red[2][threadIdx.x] + (double)red[3][threadIdx.x];
    atomicAdd(&colsum[threadIdx.x], s);
  }
}

__global__ void loss_k(const double* __restrict__ colsum, float* __restrict__ out) {
  if (threadIdx.x == 0 && blockIdx.x == 0) {
    double m = 0.0;
    for (int k = 0; k < 16; ++k) m += colsum[k];
    m *= (1.0 / 16.0);
    double var = 0.0;
    for (int k = 0; k < 16; ++k) { const double d = colsum[k] - m; var += d * d; }
    var *= (1.0 / 15.0);  // ddof=1
    out[0] = (float)(var / (m * m + 1e-10));
  }
}

// ---------------- launch ----------------
extern "C" void kernel_launch(void* const* d_in, const int* in_sizes, int n_in,
                              void* d_out, int out_size, void* d_ws, size_t ws_size,
                              hipStream_t stream) {
  const int*   x    = (const int*)d_in[0];
  const int*   sql  = (const int*)d_in[1];
  const float* sqlT = (const float*)d_in[2];
  const float* inT  = (const float*)d_in[3];
  const float* gW1  = (const float*)d_in[4];
  const float* gb1  = (const float*)d_in[5];
  const float* gW2  = (const float*)d_in[6];
  const float* gb2  = (const float*)d_in[7];
  const float* eW1  = (const float*)d_in[8];
  const float* eb1  = (const float*)d_in[9];
  const float* eW2  = (const float*)d_in[10];
  const float* eb2  = (const float*)d_in[11];

  char* ws = (char*)d_ws;
  unsigned short* eW1T = (unsigned short*)(ws);              // [16384][1280] bf16
  unsigned short* xemb = (unsigned short*)(ws + 41943040);   // [8192][1280]
  unsigned short* semb = (unsigned short*)(ws + 62914560);   // [8192][320]
  unsigned short* gW1T = (unsigned short*)(ws + 68157440);   // [1024][320]
  float*  yk     = (float*)(ws + 68812800);                  // [8192][16]
  float*  gacc   = (float*)(ws + 69337088);                  // [8192][16]
  double* colsum = (double*)(ws + 69861376);                 // [16]

  hipMemsetAsync(yk, 0, 524288 * 2 + 128, stream);

  transpose_cvt<<<dim3(32, 40, 16), 256, 0, stream>>>(eW1, eW1T, 1280, 1024, 1280L * 1024, 1024L * 1280);
  transpose_cvt<<<dim3(32, 10, 1), 256, 0, stream>>>(gW1, gW1T, 320, 1024, 0, 0);
  gather_x_k<<<BATCH, 320, 0, stream>>>(x, inT, xemb);
  gather_sql_k<<<BATCH * 80 / 256, 256, 0, stream>>>(sql, sqlT, semb);

  gemm256<KX><<<dim3(16384 / 256, BATCH / 256), 512, 0, stream>>>(
      (const __bf16*)xemb, (const __bf16*)eW1T, eb1, eW2, yk);
  gemm_k<16, KS><<<dim3(HID / 128, BATCH / 128), 256, 0, stream>>>(
      (const __bf16*)semb, (const __bf16*)gW1T, gb1, gW2, gacc);

  entmax_combine<<<BATCH / 256, 256, 0, stream>>>(gacc, gb2, yk, eb2, (float*)d_out, colsum);
  loss_k<<<1, 64, 0, stream>>>(colsum, (float*)d_out + BATCH);
}

// Round 12
// 506.705 us; speedup vs baseline: 1.2047x; 1.0203x over previous
//
#include <hip/hip_runtime.h>
#include <stdint.h>

#define NFIELD 20
#define HID 1024
#define KEXP 16
#define KX 1280   // nfield * data_nemb
#define KS 320    // nfield * sql_nemb
#define BATCH 8192

typedef __bf16 bf16x8 __attribute__((ext_vector_type(8)));
typedef float f32x4 __attribute__((ext_vector_type(4)));

__device__ __forceinline__ unsigned short f2bf(float f) {
  union { float f; unsigned u; } v; v.f = f;
  unsigned r = v.u + 0x7FFFu + ((v.u >> 16) & 1u);  // RNE
  return (unsigned short)(r >> 16);
}

__device__ __forceinline__ void gload16(const void* g, void* l) {
  __builtin_amdgcn_global_load_lds(
      (const __attribute__((address_space(1))) unsigned int*)(uintptr_t)g,
      (__attribute__((address_space(3))) unsigned int*)(unsigned)(uintptr_t)l,
      16, 0, 0);
}

#define SBAR() asm volatile("s_barrier" ::: "memory")

// ---------------- prep kernels ----------------

__global__ void transpose_cvt(const float* __restrict__ src, unsigned short* __restrict__ dst,
                              int R, int C, long sstride, long dstride) {
  __shared__ float tile[32][33];
  const float* s = src + (size_t)blockIdx.z * sstride;
  unsigned short* d = dst + (size_t)blockIdx.z * dstride;
  const int r0 = blockIdx.y * 32, c0 = blockIdx.x * 32;
  const int tx = threadIdx.x & 31, ty = threadIdx.x >> 5;
#pragma unroll
  for (int i = 0; i < 4; ++i)
    tile[ty + 8 * i][tx] = s[(size_t)(r0 + ty + 8 * i) * C + c0 + tx];
  __syncthreads();
#pragma unroll
  for (int i = 0; i < 4; ++i)
    d[(size_t)(c0 + ty + 8 * i) * R + r0 + tx] = f2bf(tile[tx][ty + 8 * i]);
}

__global__ void gather_x_k(const int* __restrict__ x, const float* __restrict__ tab,
                           unsigned short* __restrict__ out) {
  const int b = blockIdx.x;
  const int f = threadIdx.x >> 4;
  const int q = threadIdx.x & 15;
  const int idx = x[b * NFIELD + f];
  const float4 v = *(const float4*)(tab + (size_t)idx * 64 + q * 4);
  ushort4 o;
  o.x = f2bf(v.x); o.y = f2bf(v.y); o.z = f2bf(v.z); o.w = f2bf(v.w);
  *(ushort4*)(out + (size_t)b * KX + f * 64 + q * 4) = o;
}

__global__ void gather_sql_k(const int* __restrict__ sql, const float* __restrict__ tab,
                             unsigned short* __restrict__ out) {
  const int t = blockIdx.x * 256 + threadIdx.x;
  const int b = t / 80;
  const int r = t - b * 80;
  const int f = r >> 2, q = r & 3;
  const int idx = sql[b * NFIELD + f];
  const float4 v = *(const float4*)(tab + (size_t)idx * 16 + q * 4);
  ushort4 o;
  o.x = f2bf(v.x); o.y = f2bf(v.y); o.z = f2bf(v.z); o.w = f2bf(v.w);
  *(ushort4*)(out + (size_t)b * KS + f * 16 + q * 4) = o;
}

// ---------------- 128x128 / BK=64 fragment-pipelined GEMM (race-fixed) ----------------
// C = A[M,K] * Bt[N,K]^T ; epilogue: relu(acc+bias) dot W2 column-slices -> atomic out.
// 4 waves (2x2), 64x64 per wave, LDS 64 KiB -> 2 blocks/CU. Frag reads(t+1) overlap
// kk1(t)'s MFMA cluster. R11 race fix: vmcnt is PER-WAVE, so the wait covering
// stage(t+1) must precede a barrier before ANY wave reads tile t+1 (cross-wave writes).
// Tile body: {kk0(CUR); lgkm(0); vmcnt(0); SBAR; stage(t+2); readfr(t+1->NXT); kk1(CUR); SBAR}
//  - lgkm(0)+vmcnt(0)+SBAR: all waves' buf[t&1] reads retired AND all waves' stage(t+1)
//    LDS-writes landed => stage(t+2) overwrite safe + readfr(t+1) reads valid data.
// Two named frag sets, static indexing (rule #20); no sched_barrier (m141).
template <int NJO, int KTOT>
__global__ __launch_bounds__(256, 2) void gemm_k(const __bf16* __restrict__ A,
                                                 const __bf16* __restrict__ Bt,
                                                 const float* __restrict__ bias,
                                                 const float* __restrict__ W2,
                                                 float* __restrict__ out) {
  constexpr int NT = KTOT / 64;
  static_assert(NT >= 3, "pipeline needs NT>=3");
  alignas(16) __shared__ __bf16 As[2][128][64];
  alignas(16) __shared__ __bf16 Bs[2][128][64];

  const int tid = threadIdx.x;
  const int lane = tid & 63;
  const int wave = tid >> 6;        // 0..3
  const int wr = wave >> 1;         // 0..1 : M half (64 rows)
  const int wc = wave & 1;          // 0..1 : N half (64 cols)

  // L2-aware 2-level swizzle: XCD chunk + 8-wide n-groups, m-major within chunk.
  const unsigned f = blockIdx.y * gridDim.x + blockIdx.x;
  const unsigned nwg = gridDim.x * gridDim.y;
  const unsigned s = (f >> 3) + (f & 7u) * (nwg >> 3);
  const int m0 = (int)((s & 511u) >> 3) * 128;
  const int n0 = (int)((s >> 9) * 8 + (s & 7u)) * 128;

  // staging map: gload j covers 8 rows; lane l -> row j*8 + l/8, global chunk (l&7)^(l/8)
  // => LDS[r][p] holds global chunk p^(r&7)  (both-sides swizzle, linear LDS dest)
  const int srow = lane >> 3;
  const int sch = (lane & 7) ^ srow;
  const int r15 = lane & 15, g4 = lane >> 4;

  const __bf16* Ag = A + (size_t)(m0 + wave * 32 + srow) * KTOT + sch * 8;
  const __bf16* Bg = Bt + (size_t)(n0 + wave * 32 + srow) * KTOT + sch * 8;

  auto stage = [&](int t) {
    const int c = t & 1;
#pragma unroll
    for (int j = 0; j < 4; ++j)
      gload16(Ag + (size_t)(j * 8) * KTOT + t * 64, (void*)&As[c][wave * 32 + j * 8][0]);
#pragma unroll
    for (int j = 0; j < 4; ++j)
      gload16(Bg + (size_t)(j * 8) * KTOT + t * 64, (void*)&Bs[c][wave * 32 + j * 8][0]);
  };
  auto readfr = [&](int c, bf16x8 (&af)[4][2], bf16x8 (&bfr)[4][2]) {
#pragma unroll
    for (int mi = 0; mi < 4; ++mi) {
      const int row = wr * 64 + mi * 16 + r15;
#pragma unroll
      for (int kk = 0; kk < 2; ++kk)
        af[mi][kk] = *(const bf16x8*)&As[c][row][((kk * 4 + g4) ^ (row & 7)) * 8];
    }
#pragma unroll
    for (int ni = 0; ni < 4; ++ni) {
      const int row = wc * 64 + ni * 16 + r15;
#pragma unroll
      for (int kk = 0; kk < 2; ++kk)
        bfr[ni][kk] = *(const bf16x8*)&Bs[c][row][((kk * 4 + g4) ^ (row & 7)) * 8];
    }
  };

  f32x4 acc[4][4] = {};
  bf16x8 afA[4][2], bfA[4][2], afB[4][2], bfB[4][2];

#define MFMA16(AF, BF, KK)                                                     \
  __builtin_amdgcn_s_setprio(1);                                               \
  _Pragma("unroll") for (int mi = 0; mi < 4; ++mi)                             \
  _Pragma("unroll") for (int ni = 0; ni < 4; ++ni)                             \
      acc[mi][ni] = __builtin_amdgcn_mfma_f32_16x16x32_bf16(                   \
          AF[mi][KK], BF[ni][KK], acc[mi][ni], 0, 0, 0);                       \
  __builtin_amdgcn_s_setprio(0);

#define BODY(T, AFC, BFC, AFN, BFN)                                            \
  MFMA16(AFC, BFC, 0);                                                         \
  asm volatile("s_waitcnt lgkmcnt(0)" ::: "memory");                           \
  asm volatile("s_waitcnt vmcnt(0)" ::: "memory");                             \
  SBAR();                                                                      \
  if ((T) + 2 < NT) stage((T) + 2);                                            \
  readfr(((T) + 1) & 1, AFN, BFN);                                             \
  MFMA16(AFC, BFC, 1);                                                         \
  SBAR();

  // prologue: stage tiles 0,1; wait own tile0+tile1... (vmcnt(0) + SBAR gives all-wave
  // guarantee for tile0 AND tile1 -- simple and safe); prefetch frags(0)
  stage(0);
  stage(1);
  asm volatile("s_waitcnt vmcnt(0)" ::: "memory");
  SBAR();
  readfr(0, afA, bfA);

  int t = 0;
  for (; t + 1 < NT - 1; t += 2) {
    BODY(t, afA, bfA, afB, bfB);
    BODY(t + 1, afB, bfB, afA, bfA);
  }
  if constexpr (((NT - 1) & 1) != 0) {
    BODY(NT - 2, afA, bfA, afB, bfB);
    // tail t = NT-1 (odd index -> set B), no prefetch
    MFMA16(afB, bfB, 0);
    MFMA16(afB, bfB, 1);
  } else {
    // tail t = NT-1 (even index -> set A), no prefetch
    MFMA16(afA, bfA, 0);
    MFMA16(afA, bfA, 1);
  }
#undef BODY
#undef MFMA16

  // epilogue: relu(acc+bias), weighted column reduce, atomic accumulate
  int ncol[4];
  float bsv[4];
#pragma unroll
  for (int ni = 0; ni < 4; ++ni) {
    ncol[ni] = n0 + wc * 64 + ni * 16 + r15;  // C/D: col = lane&15
    bsv[ni] = bias[ncol[ni]];
  }
#pragma unroll
  for (int mi = 0; mi < 4; ++mi)
#pragma unroll
    for (int ni = 0; ni < 4; ++ni)
#pragma unroll
      for (int j = 0; j < 4; ++j) {
        float v = acc[mi][ni][j] + bsv[ni];
        acc[mi][ni][j] = v > 0.f ? v : 0.f;
      }
#pragma unroll
  for (int jo = 0; jo < NJO; ++jo) {
    float w4[4];
#pragma unroll
    for (int ni = 0; ni < 4; ++ni)
      w4[ni] = (NJO == 1) ? W2[ncol[ni]] : W2[ncol[ni] * NJO + jo];
#pragma unroll
    for (int mi = 0; mi < 4; ++mi)
#pragma unroll
      for (int j = 0; j < 4; ++j) {
        float s = acc[mi][0][j] * w4[0] + acc[mi][1][j] * w4[1] +
                  acc[mi][2][j] * w4[2] + acc[mi][3][j] * w4[3];
        s += __shfl_xor(s, 1);
        s += __shfl_xor(s, 2);
        s += __shfl_xor(s, 4);
        s += __shfl_xor(s, 8);
        if (r15 == 0) {
          const int row = m0 + wr * 64 + mi * 16 + g4 * 4 + j;  // C/D: row=(lane>>4)*4+reg
          const int oc = (NJO == 1) ? (n0 >> 10) : jo;
          atomicAdd(&out[row * KEXP + oc], s);
        }
      }
  }
}

// ---------------- entmax (alpha=1.5, 50 bisect iters) + combine + gate colsums ------------
__global__ void entmax_combine(const float* __restrict__ gacc, const float* __restrict__ gb2,
                               const float* __restrict__ yk, const float* __restrict__ eb2,
                               float* __restrict__ y, double* __restrict__ colsum) {
  const int b = blockIdx.x * 256 + threadIdx.x;
  float x[16];
  float mx = -3.4e38f;
#pragma unroll
  for (int j = 0; j < 16; ++j) {
    x[j] = (gacc[b * 16 + j] + gb2[j]) * 0.5f;  // * (alpha-1)
    mx = fmaxf(mx, x[j]);
  }
  float lo = mx - 1.0f, hi = mx - 0.25f;  // d^(1-alpha) = 16^-0.5
  float flo = -1.0f;
#pragma unroll
  for (int j = 0; j < 16; ++j) {
    float d = x[j] - lo; d = d > 0.f ? d : 0.f;
    flo += d * d;
  }
  for (int it = 0; it < 50; ++it) {
    const float tm = 0.5f * (lo + hi);
    float fm = -1.0f;
#pragma unroll
    for (int j = 0; j < 16; ++j) {
      float d = x[j] - tm; d = d > 0.f ? d : 0.f;
      fm += d * d;
    }
    if (fm * flo >= 0.f) { lo = tm; flo = fm; } else { hi = tm; }
  }
  const float tm = 0.5f * (lo + hi);
  float p[16], ps = 0.f;
#pragma unroll
  for (int j = 0; j < 16; ++j) {
    float d = x[j] - tm; d = d > 0.f ? d : 0.f;
    p[j] = d * d; ps += p[j];
  }
  const float inv = 1.0f / ps;
  float yv = 0.f;
#pragma unroll
  for (int j = 0; j < 16; ++j) {
    p[j] *= inv;
    yv += p[j] * (yk[b * 16 + j] + eb2[j]);
  }
  y[b] = yv;

  const int lane = threadIdx.x & 63, wv = threadIdx.x >> 6;
  __shared__ float red[4][16];
#pragma unroll
  for (int j = 0; j < 16; ++j) {
    float v = p[j];
    v += __shfl_xor(v, 1);  v += __shfl_xor(v, 2);  v += __shfl_xor(v, 4);
    v += __shfl_xor(v, 8);  v += __shfl_xor(v, 16); v += __shfl_xor(v, 32);
    if (lane == 0) red[wv][j] = v;
  }
  __syncthreads();
  if (threadIdx.x < 16) {
    double s = (double)red[0][threadIdx.x] + (double)red[1][threadIdx.x] +
               (double)red[2][threadIdx.x] + (double)red[3][threadIdx.x];
    atomicAdd(&colsum[threadIdx.x], s);
  }
}

__global__ void loss_k(const double* __restrict__ colsum, float* __restrict__ out) {
  if (threadIdx.x == 0 && blockIdx.x == 0) {
    double m = 0.0;
    for (int k = 0; k < 16; ++k) m += colsum[k];
    m *= (1.0 / 16.0);
    double var = 0.0;
    for (int k = 0; k < 16; ++k) { const double d = colsum[k] - m; var += d * d; }
    var *= (1.0 / 15.0);  // ddof=1
    out[0] = (float)(var / (m * m + 1e-10));
  }
}

// ---------------- launch ----------------
extern "C" void kernel_launch(void* const* d_in, const int* in_sizes, int n_in,
                              void* d_out, int out_size, void* d_ws, size_t ws_size,
                              hipStream_t stream) {
  const int*   x    = (const int*)d_in[0];
  const int*   sql  = (const int*)d_in[1];
  const float* sqlT = (const float*)d_in[2];
  const float* inT  = (const float*)d_in[3];
  const float* gW1  = (const float*)d_in[4];
  const float* gb1  = (const float*)d_in[5];
  const float* gW2  = (const float*)d_in[6];
  const float* gb2  = (const float*)d_in[7];
  const float* eW1  = (const float*)d_in[8];
  const float* eb1  = (const float*)d_in[9];
  const float* eW2  = (const float*)d_in[10];
  const float* eb2  = (const float*)d_in[11];

  char* ws = (char*)d_ws;
  unsigned short* eW1T = (unsigned short*)(ws);              // [16384][1280] bf16
  unsigned short* xemb = (unsigned short*)(ws + 41943040);   // [8192][1280]
  unsigned short* semb = (unsigned short*)(ws + 62914560);   // [8192][320]
  unsigned short* gW1T = (unsigned short*)(ws + 68157440);   // [1024][320]
  float*  yk     = (float*)(ws + 68812800);                  // [8192][16]
  float*  gacc   = (float*)(ws + 69337088);                  // [8192][16]
  double* colsum = (double*)(ws + 69861376);                 // [16]

  hipMemsetAsync(yk, 0, 524288 * 2 + 128, stream);

  transpose_cvt<<<dim3(32, 40, 16), 256, 0, stream>>>(eW1, eW1T, 1280, 1024, 1280L * 1024, 1024L * 1280);
  transpose_cvt<<<dim3(32, 10, 1), 256, 0, stream>>>(gW1, gW1T, 320, 1024, 0, 0);
  gather_x_k<<<BATCH, 320, 0, stream>>>(x, inT, xemb);
  gather_sql_k<<<BATCH * 80 / 256, 256, 0, stream>>>(sql, sqlT, semb);

  gemm_k<1, KX><<<dim3(16384 / 128, BATCH / 128), 256, 0, stream>>>(
      (const __bf16*)xemb, (const __bf16*)eW1T, eb1, eW2, yk);
  gemm_k<16, KS><<<dim3(HID / 128, BATCH / 128), 256, 0, stream>>>(
      (const __bf16*)semb, (const __bf16*)gW1T, gb1, gW2, gacc);

  entmax_combine<<<BATCH / 256, 256, 0, stream>>>(gacc, gb2, yk, eb2, (float*)d_out, colsum);
  loss_k<<<1, 64, 0, stream>>>(colsum, (float*)d_out + BATCH);
}